// Round 4
// baseline (1558.345 us; speedup 1.0000x reference)
//
#include <hip/hip_runtime.h>

#define D 64
#define D4 16   // D/4 float4 per row

typedef float4 f4;

__device__ __forceinline__ float leaky02(float x) { return (x >= 0.f) ? x : 0.2f * x; }

__device__ __forceinline__ float bcast(float v, int k) {
    return __uint_as_float(__builtin_amdgcn_readlane(__float_as_uint(v), k));
}

__device__ __forceinline__ f4 f4add(f4 a, f4 b) {
    return make_float4(a.x + b.x, a.y + b.y, a.z + b.z, a.w + b.w);
}
__device__ __forceinline__ f4 f4fma(float s, f4 v, f4 a) {
    return make_float4(fmaf(s, v.x, a.x), fmaf(s, v.y, a.y), fmaf(s, v.z, a.z), fmaf(s, v.w, a.w));
}
__device__ __forceinline__ f4 f4scale(f4 a, float s) {
    return make_float4(a.x * s, a.y * s, a.z * s, a.w * s);
}

// ---------------- CSR build ----------------

__global__ __launch_bounds__(256) void hist_kernel(const int* __restrict__ dst,
                                                   int* __restrict__ cnt, int ne) {
    int e = blockIdx.x * blockDim.x + threadIdx.x;
    if (e < ne) atomicAdd(&cnt[dst[e]], 1);
}

#define SCAN_BS 256
__global__ __launch_bounds__(SCAN_BS) void scan1_kernel(const int* __restrict__ cnt,
                                                        int* __restrict__ incl,
                                                        int* __restrict__ partials, int n) {
    __shared__ int sm[SCAN_BS];
    int g = blockIdx.x * SCAN_BS + threadIdx.x;
    int v = (g < n) ? cnt[g] : 0;
    sm[threadIdx.x] = v;
    __syncthreads();
    for (int off = 1; off < SCAN_BS; off <<= 1) {
        int t = (threadIdx.x >= off) ? sm[threadIdx.x - off] : 0;
        __syncthreads();
        sm[threadIdx.x] += t;
        __syncthreads();
    }
    if (g < n) incl[g] = sm[threadIdx.x];
    if (threadIdx.x == SCAN_BS - 1) partials[blockIdx.x] = sm[threadIdx.x];
}

__global__ __launch_bounds__(1024) void scan2_kernel(int* __restrict__ partials, int nb) {
    __shared__ int sm[1024];
    int t = threadIdx.x;
    int v = (t < nb) ? partials[t] : 0;
    sm[t] = v;
    __syncthreads();
    for (int off = 1; off < 1024; off <<= 1) {
        int x = (t >= off) ? sm[t - off] : 0;
        __syncthreads();
        sm[t] += x;
        __syncthreads();
    }
    if (t < nb) partials[t] = sm[t] - v;   // exclusive
}

__global__ __launch_bounds__(SCAN_BS) void scan3_kernel(const int* __restrict__ cnt,
                                                        const int* __restrict__ incl,
                                                        const int* __restrict__ partials,
                                                        int* __restrict__ rowptr,
                                                        int* __restrict__ cursor, int n, int ne) {
    int g = blockIdx.x * SCAN_BS + threadIdx.x;
    if (g < n) {
        int rp = incl[g] - cnt[g] + partials[blockIdx.x];
        rowptr[g] = rp;
        cursor[g] = rp;
    }
    if (g == 0) rowptr[n] = ne;
}

__global__ __launch_bounds__(256) void fill_kernel(const int* __restrict__ src,
                                                   const int* __restrict__ dst,
                                                   int* __restrict__ cursor,
                                                   int* __restrict__ col, int ne) {
    int e = blockIdx.x * blockDim.x + threadIdx.x;
    if (e < ne) {
        int pos = atomicAdd(&cursor[dst[e]], 1);
        col[pos] = src[e];
    }
}

// ---------------- SAGE dense: Yl = h@Wl.T ; Zr = h@Wr.T + bl ----------------

__global__ __launch_bounds__(256) void sage_dense(const float* __restrict__ h,
                                                  const float* __restrict__ Wl,
                                                  const float* __restrict__ bl,
                                                  const float* __restrict__ Wr,
                                                  float* __restrict__ Yl,
                                                  float* __restrict__ Zr, int n) {
    __shared__ float wl[D][D + 1];
    __shared__ float wr[D][D + 1];
    for (int idx = threadIdx.x; idx < D * D; idx += 256) {
        wl[idx >> 6][idx & 63] = Wl[idx];
        wr[idx >> 6][idx & 63] = Wr[idx];
    }
    __syncthreads();
    int wid = threadIdx.x >> 6, lane = threadIdx.x & 63;
    float blv = bl[lane];
    int step = gridDim.x * 32;
    for (int nb = (blockIdx.x * 4 + wid) * 8; nb < n; nb += step) {
        int cnt = min(8, n - nb);
        float hv[8];
#pragma unroll
        for (int j = 0; j < 8; j++)
            hv[j] = (j < cnt) ? h[(size_t)(nb + j) * D + lane] : 0.f;
        float accY[8], accZ[8];
#pragma unroll
        for (int j = 0; j < 8; j++) { accY[j] = 0.f; accZ[j] = blv; }
#pragma unroll
        for (int k = 0; k < D; k++) {
            float wlk = wl[lane][k], wrk = wr[lane][k];
#pragma unroll
            for (int j = 0; j < 8; j++) {
                float hk = bcast(hv[j], k);
                accY[j] = fmaf(hk, wlk, accY[j]);
                accZ[j] = fmaf(hk, wrk, accZ[j]);
            }
        }
#pragma unroll
        for (int j = 0; j < 8; j++)
            if (j < cnt) {
                Yl[(size_t)(nb + j) * D + lane] = accY[j];
                Zr[(size_t)(nb + j) * D + lane] = accZ[j];
            }
    }
}

// ---------------- SAGE gather: out = relu(mean_j Yl[j] + Zr[i]) ----------------
// 16 lanes per node (float4), 8-deep ILP.

__global__ __launch_bounds__(256) void sage_gather(const f4* __restrict__ Yl,
                                                   const f4* __restrict__ Zr,
                                                   const int* __restrict__ rowptr,
                                                   const int* __restrict__ col,
                                                   f4* __restrict__ out,
                                                   int relu_flag, int n) {
    int t = blockIdx.x * 256 + threadIdx.x;
    int l16 = t & 15;
    int gbase = (threadIdx.x & 63) & 48;
    int stride = (gridDim.x * 256) >> 4;
    for (int node = t >> 4; node < n; node += stride) {
        int start = rowptr[node], end = rowptr[node + 1];
        f4 a0 = {0, 0, 0, 0}, a1 = {0, 0, 0, 0}, a2 = {0, 0, 0, 0}, a3 = {0, 0, 0, 0};
        for (int base = start; base < end; base += 16) {
            int idx = base + l16;
            int s_l = (idx < end) ? col[idx] : 0;
            int cnt = min(16, end - base);
            int i = 0;
            for (; i + 7 < cnt; i += 8) {
                int s0 = __shfl(s_l, gbase + i);
                int s1 = __shfl(s_l, gbase + i + 1);
                int s2 = __shfl(s_l, gbase + i + 2);
                int s3 = __shfl(s_l, gbase + i + 3);
                int s4 = __shfl(s_l, gbase + i + 4);
                int s5 = __shfl(s_l, gbase + i + 5);
                int s6 = __shfl(s_l, gbase + i + 6);
                int s7 = __shfl(s_l, gbase + i + 7);
                f4 r0 = Yl[(size_t)s0 * D4 + l16];
                f4 r1 = Yl[(size_t)s1 * D4 + l16];
                f4 r2 = Yl[(size_t)s2 * D4 + l16];
                f4 r3 = Yl[(size_t)s3 * D4 + l16];
                f4 r4 = Yl[(size_t)s4 * D4 + l16];
                f4 r5 = Yl[(size_t)s5 * D4 + l16];
                f4 r6 = Yl[(size_t)s6 * D4 + l16];
                f4 r7 = Yl[(size_t)s7 * D4 + l16];
                a0 = f4add(a0, r0); a1 = f4add(a1, r1);
                a2 = f4add(a2, r2); a3 = f4add(a3, r3);
                a0 = f4add(a0, r4); a1 = f4add(a1, r5);
                a2 = f4add(a2, r6); a3 = f4add(a3, r7);
            }
            for (; i < cnt; i++) {
                int s = __shfl(s_l, gbase + i);
                a0 = f4add(a0, Yl[(size_t)s * D4 + l16]);
            }
        }
        f4 a = f4add(f4add(a0, a1), f4add(a2, a3));
        float invd = 1.f / fmaxf((float)(end - start), 1.f);
        f4 z = Zr[(size_t)node * D4 + l16];
        f4 o = make_float4(fmaf(a.x, invd, z.x), fmaf(a.y, invd, z.y),
                           fmaf(a.z, invd, z.z), fmaf(a.w, invd, z.w));
        if (relu_flag) {
            o.x = fmaxf(o.x, 0.f); o.y = fmaxf(o.y, 0.f);
            o.z = fmaxf(o.z, 0.f); o.w = fmaxf(o.w, 0.f);
        }
        out[(size_t)node * D4 + l16] = o;
    }
}

// ---------------- GAT dense: ht = h@W.T ; as = ht.a_src ; ad = ht.a_dst ----------------

__global__ __launch_bounds__(256) void gat_transform(const float* __restrict__ h,
                                                     const float* __restrict__ W,
                                                     const float* __restrict__ a_src,
                                                     const float* __restrict__ a_dst,
                                                     float* __restrict__ ht,
                                                     float* __restrict__ as_,
                                                     float* __restrict__ ad_, int n) {
    __shared__ float w[D][D + 1];
    for (int idx = threadIdx.x; idx < D * D; idx += 256)
        w[idx >> 6][idx & 63] = W[idx];
    __syncthreads();
    int wid = threadIdx.x >> 6, lane = threadIdx.x & 63;
    float a0 = a_src[lane], a1 = a_dst[lane];
    int step = gridDim.x * 32;
    for (int nb = (blockIdx.x * 4 + wid) * 8; nb < n; nb += step) {
        int cnt = min(8, n - nb);
        float hv[8];
#pragma unroll
        for (int j = 0; j < 8; j++)
            hv[j] = (j < cnt) ? h[(size_t)(nb + j) * D + lane] : 0.f;
        float acc[8];
#pragma unroll
        for (int j = 0; j < 8; j++) acc[j] = 0.f;
#pragma unroll
        for (int k = 0; k < D; k++) {
            float wk = w[lane][k];
#pragma unroll
            for (int j = 0; j < 8; j++)
                acc[j] = fmaf(bcast(hv[j], k), wk, acc[j]);
        }
#pragma unroll
        for (int j = 0; j < 8; j++) {
            if (j < cnt) ht[(size_t)(nb + j) * D + lane] = acc[j];
            float s = acc[j] * a0;
            float d = acc[j] * a1;
#pragma unroll
            for (int off = 32; off > 0; off >>= 1) {
                s += __shfl_xor(s, off);
                d += __shfl_xor(d, off);
            }
            if (lane == 0 && j < cnt) { as_[nb + j] = s; ad_[nb + j] = d; }
        }
    }
}

// ---------------- GAT gather: single-pass online softmax + weighted agg ----------------

__global__ __launch_bounds__(256) void gat_gather(const int* __restrict__ rowptr,
                                                  const int* __restrict__ col,
                                                  const float* __restrict__ as_,
                                                  const float* __restrict__ ad_,
                                                  const f4* __restrict__ ht,
                                                  const float* __restrict__ b,
                                                  f4* __restrict__ out,
                                                  int relu_flag, int n) {
    int t = blockIdx.x * 256 + threadIdx.x;
    int l16 = t & 15;
    int gbase = (threadIdx.x & 63) & 48;
    int stride = (gridDim.x * 256) >> 4;
    const f4* b4 = (const f4*)b;
    for (int node = t >> 4; node < n; node += stride) {
        int start = rowptr[node], end = rowptr[node + 1];
        float ad_n = ad_[node];
        float e_self = leaky02(as_[node] + ad_n);
        // running state: softmax relative to m (starts at self-loop)
        float m = e_self;
        float z0 = 1.f, z1 = 0.f, z2 = 0.f, z3 = 0.f;   // exp(e_self - m) = 1
        f4 acc0 = ht[(size_t)node * D4 + l16];
        f4 acc1 = {0, 0, 0, 0}, acc2 = {0, 0, 0, 0}, acc3 = {0, 0, 0, 0};
        for (int base = start; base < end; base += 16) {
            int idx = base + l16;
            int cnt = min(16, end - base);
            int s_l = (idx < end) ? col[idx] : 0;
            float e_l = (idx < end) ? leaky02(as_[s_l] + ad_n) : -3.4e38f;
            // chunk max (uniform across the 16-lane group)
            float cm = e_l;
#pragma unroll
            for (int off = 8; off > 0; off >>= 1)
                cm = fmaxf(cm, __shfl_xor(cm, off));
            if (cm > m) {
                float sc = __expf(m - cm);
                z0 *= sc; z1 *= sc; z2 *= sc; z3 *= sc;
                acc0 = f4scale(acc0, sc); acc1 = f4scale(acc1, sc);
                acc2 = f4scale(acc2, sc); acc3 = f4scale(acc3, sc);
                m = cm;
            }
            float p_l = (idx < end) ? __expf(e_l - m) : 0.f;
            int i = 0;
            for (; i + 3 < cnt; i += 4) {
                int s0 = __shfl(s_l, gbase + i);
                int s1 = __shfl(s_l, gbase + i + 1);
                int s2 = __shfl(s_l, gbase + i + 2);
                int s3 = __shfl(s_l, gbase + i + 3);
                float p0 = __shfl(p_l, gbase + i);
                float p1 = __shfl(p_l, gbase + i + 1);
                float p2 = __shfl(p_l, gbase + i + 2);
                float p3 = __shfl(p_l, gbase + i + 3);
                f4 r0 = ht[(size_t)s0 * D4 + l16];
                f4 r1 = ht[(size_t)s1 * D4 + l16];
                f4 r2 = ht[(size_t)s2 * D4 + l16];
                f4 r3 = ht[(size_t)s3 * D4 + l16];
                z0 += p0; z1 += p1; z2 += p2; z3 += p3;
                acc0 = f4fma(p0, r0, acc0);
                acc1 = f4fma(p1, r1, acc1);
                acc2 = f4fma(p2, r2, acc2);
                acc3 = f4fma(p3, r3, acc3);
            }
            for (; i < cnt; i++) {
                int s0 = __shfl(s_l, gbase + i);
                float p0 = __shfl(p_l, gbase + i);
                z0 += p0;
                acc0 = f4fma(p0, ht[(size_t)s0 * D4 + l16], acc0);
            }
        }
        float rz = 1.f / ((z0 + z1) + (z2 + z3));
        f4 acc = f4add(f4add(acc0, acc1), f4add(acc2, acc3));
        f4 bb = b4[l16];
        f4 o = make_float4(fmaf(acc.x, rz, bb.x), fmaf(acc.y, rz, bb.y),
                           fmaf(acc.z, rz, bb.z), fmaf(acc.w, rz, bb.w));
        if (relu_flag) {
            o.x = fmaxf(o.x, 0.f); o.y = fmaxf(o.y, 0.f);
            o.z = fmaxf(o.z, 0.f); o.w = fmaxf(o.w, 0.f);
        }
        out[(size_t)node * D4 + l16] = o;
    }
}

// ---------------- MLP: 8 nodes/wave, readlane broadcast, no inner barriers ----------------

__global__ __launch_bounds__(256) void mlp_kernel(const float* __restrict__ h,
                                                  const float* __restrict__ W1,
                                                  const float* __restrict__ b1,
                                                  const float* __restrict__ W2,
                                                  const float* __restrict__ b2,
                                                  const float* __restrict__ W3,
                                                  const float* __restrict__ b3,
                                                  float* __restrict__ out, int n) {
    __shared__ float w1[64][65];
    __shared__ float w2[32][65];
    __shared__ float w3[16][33];
    for (int idx = threadIdx.x; idx < 64 * 64; idx += 256) w1[idx >> 6][idx & 63] = W1[idx];
    for (int idx = threadIdx.x; idx < 32 * 64; idx += 256) w2[idx >> 6][idx & 63] = W2[idx];
    for (int idx = threadIdx.x; idx < 16 * 32; idx += 256) w3[idx >> 5][idx & 31] = W3[idx];
    __syncthreads();
    int wid = threadIdx.x >> 6, lane = threadIdx.x & 63;
    float b1v = b1[lane];
    float b2v = (lane < 32) ? b2[lane] : 0.f;
    float b3v = (lane < 16) ? b3[lane] : 0.f;
    int step = gridDim.x * 32;
    for (int nb = (blockIdx.x * 4 + wid) * 8; nb < n; nb += step) {
        int cnt = min(8, n - nb);
        float hv[8];
#pragma unroll
        for (int j = 0; j < 8; j++)
            hv[j] = (j < cnt) ? h[(size_t)(nb + j) * D + lane] : 0.f;
        float v1[8];
#pragma unroll
        for (int j = 0; j < 8; j++) v1[j] = b1v;
#pragma unroll
        for (int k = 0; k < 64; k++) {
            float wk = w1[lane][k];
#pragma unroll
            for (int j = 0; j < 8; j++)
                v1[j] = fmaf(bcast(hv[j], k), wk, v1[j]);
        }
#pragma unroll
        for (int j = 0; j < 8; j++) v1[j] = fmaxf(v1[j], 0.f);
        float v2[8];
#pragma unroll
        for (int j = 0; j < 8; j++) v2[j] = b2v;
#pragma unroll
        for (int k = 0; k < 64; k++) {
            float wk = (lane < 32) ? w2[lane][k] : 0.f;
#pragma unroll
            for (int j = 0; j < 8; j++)
                v2[j] = fmaf(bcast(v1[j], k), wk, v2[j]);
        }
#pragma unroll
        for (int j = 0; j < 8; j++) v2[j] = fmaxf(v2[j], 0.f);
        float v3[8];
#pragma unroll
        for (int j = 0; j < 8; j++) v3[j] = b3v;
#pragma unroll
        for (int k = 0; k < 32; k++) {
            float wk = (lane < 16) ? w3[lane][k] : 0.f;
#pragma unroll
            for (int j = 0; j < 8; j++)
                v3[j] = fmaf(bcast(v2[j], k), wk, v3[j]);
        }
        if (lane < 16) {
#pragma unroll
            for (int j = 0; j < 8; j++)
                if (j < cnt) out[(size_t)(nb + j) * 16 + lane] = v3[j];
        }
    }
}

// ---------------- launch ----------------

extern "C" void kernel_launch(void* const* d_in, const int* in_sizes, int n_in,
                              void* d_out, int out_size, void* d_ws, size_t ws_size,
                              hipStream_t stream) {
    const int n  = in_sizes[0] / D;      // 100000
    const int ne = in_sizes[1] / 2;      // 1600000

    const float* x        = (const float*)d_in[0];
    const int*   ei       = (const int*)d_in[1];
    const int*   src      = ei;
    const int*   dst      = ei + ne;
    const float* sage_Wl  = (const float*)d_in[2];
    const float* sage_bl  = (const float*)d_in[3];
    const float* sage_Wr  = (const float*)d_in[4];
    const float* gat_W    = (const float*)d_in[5];
    const float* gat_asrc = (const float*)d_in[6];
    const float* gat_adst = (const float*)d_in[7];
    const float* gat_b    = (const float*)d_in[8];
    const float* W1 = (const float*)d_in[9];
    const float* b1 = (const float*)d_in[10];
    const float* W2 = (const float*)d_in[11];
    const float* b2 = (const float*)d_in[12];
    const float* W3 = (const float*)d_in[13];
    const float* b3 = (const float*)d_in[14];
    float* out = (float*)d_out;

    // workspace layout (4B units, all offsets 16B-aligned)
    int*   cnt      = (int*)d_ws;                    // n
    int*   incl     = cnt + n;                       // n
    int*   rowptr   = incl + n;                      // n+4
    int*   cursor   = rowptr + n + 4;                // n
    int*   partials = cursor + n;                    // 1024
    int*   col      = partials + 1024;               // ne
    float* as_      = (float*)(col + ne);            // n
    float* ad_      = as_ + n;                       // n
    float* Yl       = ad_ + n;                       // n*D (also GAT ht)
    float* Zr       = Yl + (size_t)n * D;            // n*D
    float* bufA     = Zr + (size_t)n * D;            // n*D
    float* bufB     = bufA + (size_t)n * D;          // n*D

    const int gridE  = (ne + 255) / 256;
    const int nb     = (n + SCAN_BS - 1) / SCAN_BS;
    const int gridG  = (n * 16 + 255) / 256;         // 16 lanes per node
    const int gridD  = (n + 31) / 32;                // 8 nodes/wave * 4 waves

    // ---- CSR build ----
    hipMemsetAsync(cnt, 0, (size_t)n * 4, stream);
    hist_kernel<<<gridE, 256, 0, stream>>>(dst, cnt, ne);
    scan1_kernel<<<nb, SCAN_BS, 0, stream>>>(cnt, incl, partials, n);
    scan2_kernel<<<1, 1024, 0, stream>>>(partials, nb);
    scan3_kernel<<<nb, SCAN_BS, 0, stream>>>(cnt, incl, partials, rowptr, cursor, n, ne);
    fill_kernel<<<gridE, 256, 0, stream>>>(src, dst, cursor, col, ne);

    // ---- 4 SAGE layers (x -> A -> B -> A -> B) ----
    const float* cur = x;
    float* nxt = bufA;
    for (int l = 0; l < 4; l++) {
        sage_dense<<<gridD, 256, 0, stream>>>(cur,
                                              sage_Wl + (size_t)l * D * D,
                                              sage_bl + (size_t)l * D,
                                              sage_Wr + (size_t)l * D * D,
                                              Yl, Zr, n);
        sage_gather<<<gridG, 256, 0, stream>>>((const f4*)Yl, (const f4*)Zr,
                                               rowptr, col, (f4*)nxt,
                                               (l < 3) ? 1 : 0, n);
        cur = nxt;
        nxt = (nxt == bufA) ? bufB : bufA;
    }
    // cur == bufB

    // ---- 4 GAT layers (in-place on bufB, ht reuses Yl) ----
    float* gin = bufB;
    for (int l = 0; l < 4; l++) {
        gat_transform<<<gridD, 256, 0, stream>>>(gin,
                                                 gat_W + (size_t)l * D * D,
                                                 gat_asrc + (size_t)l * D,
                                                 gat_adst + (size_t)l * D,
                                                 Yl, as_, ad_, n);
        gat_gather<<<gridG, 256, 0, stream>>>(rowptr, col, as_, ad_,
                                              (const f4*)Yl,
                                              gat_b + (size_t)l * D, (f4*)gin,
                                              (l < 3) ? 1 : 0, n);
    }

    // ---- projection MLP ----
    mlp_kernel<<<gridD, 256, 0, stream>>>(gin, W1, b1, W2, b2, W3, b3, out, n);
}

// Round 5
// 1483.113 us; speedup vs baseline: 1.0507x; 1.0507x over previous
//
#include <hip/hip_runtime.h>

#define D 64
#define D4 16   // D/4 float4 per row

typedef float4 f4;

__device__ __forceinline__ float leaky02(float x) { return (x >= 0.f) ? x : 0.2f * x; }

__device__ __forceinline__ f4 f4add(f4 a, f4 b) {
    return make_float4(a.x + b.x, a.y + b.y, a.z + b.z, a.w + b.w);
}
__device__ __forceinline__ f4 f4fma(float s, f4 v, f4 a) {
    return make_float4(fmaf(s, v.x, a.x), fmaf(s, v.y, a.y), fmaf(s, v.z, a.z), fmaf(s, v.w, a.w));
}
__device__ __forceinline__ f4 f4scale(f4 a, float s) {
    return make_float4(a.x * s, a.y * s, a.z * s, a.w * s);
}

// ---------------- CSR build ----------------

__global__ __launch_bounds__(256) void hist_kernel(const int* __restrict__ dst,
                                                   int* __restrict__ cnt, int ne) {
    int e = blockIdx.x * blockDim.x + threadIdx.x;
    if (e < ne) atomicAdd(&cnt[dst[e]], 1);
}

#define SCAN_BS 256
__global__ __launch_bounds__(SCAN_BS) void scan1_kernel(const int* __restrict__ cnt,
                                                        int* __restrict__ incl,
                                                        int* __restrict__ partials, int n) {
    __shared__ int sm[SCAN_BS];
    int g = blockIdx.x * SCAN_BS + threadIdx.x;
    int v = (g < n) ? cnt[g] : 0;
    sm[threadIdx.x] = v;
    __syncthreads();
    for (int off = 1; off < SCAN_BS; off <<= 1) {
        int t = (threadIdx.x >= off) ? sm[threadIdx.x - off] : 0;
        __syncthreads();
        sm[threadIdx.x] += t;
        __syncthreads();
    }
    if (g < n) incl[g] = sm[threadIdx.x];
    if (threadIdx.x == SCAN_BS - 1) partials[blockIdx.x] = sm[threadIdx.x];
}

__global__ __launch_bounds__(1024) void scan2_kernel(int* __restrict__ partials, int nb) {
    __shared__ int sm[1024];
    int t = threadIdx.x;
    int v = (t < nb) ? partials[t] : 0;
    sm[t] = v;
    __syncthreads();
    for (int off = 1; off < 1024; off <<= 1) {
        int x = (t >= off) ? sm[t - off] : 0;
        __syncthreads();
        sm[t] += x;
        __syncthreads();
    }
    if (t < nb) partials[t] = sm[t] - v;   // exclusive
}

__global__ __launch_bounds__(SCAN_BS) void scan3_kernel(const int* __restrict__ cnt,
                                                        const int* __restrict__ incl,
                                                        const int* __restrict__ partials,
                                                        int* __restrict__ rowptr,
                                                        int* __restrict__ cursor, int n, int ne) {
    int g = blockIdx.x * SCAN_BS + threadIdx.x;
    if (g < n) {
        int rp = incl[g] - cnt[g] + partials[blockIdx.x];
        rowptr[g] = rp;
        cursor[g] = rp;
    }
    if (g == 0) rowptr[n] = ne;
}

__global__ __launch_bounds__(256) void fill_kernel(const int* __restrict__ src,
                                                   const int* __restrict__ dst,
                                                   int* __restrict__ cursor,
                                                   int* __restrict__ col, int ne) {
    int e = blockIdx.x * blockDim.x + threadIdx.x;
    if (e < ne) {
        int pos = atomicAdd(&cursor[dst[e]], 1);
        col[pos] = src[e];
    }
}

// ---------------- SAGE dense: Yl = h@Wl.T ; Zr = h@Wr.T + bl ----------------
// One thread per node; weights via wave-uniform (scalar) loads.

__global__ __launch_bounds__(256) void sage_dense(const float* __restrict__ h,
                                                  const float* __restrict__ Wl,
                                                  const float* __restrict__ bl,
                                                  const float* __restrict__ Wr,
                                                  float* __restrict__ Yl,
                                                  float* __restrict__ Zr, int n) {
    int node = blockIdx.x * 256 + threadIdx.x;
    if (node >= n) return;
    float hreg[64];
    const f4* hp = (const f4*)(h + (size_t)node * D);
#pragma unroll
    for (int i = 0; i < 16; i++) {
        f4 r = hp[i];
        hreg[4 * i] = r.x; hreg[4 * i + 1] = r.y;
        hreg[4 * i + 2] = r.z; hreg[4 * i + 3] = r.w;
    }
    f4* yp = (f4*)(Yl + (size_t)node * D);
    f4* zp = (f4*)(Zr + (size_t)node * D);
    for (int og = 0; og < 16; og++) {
        const float* w = Wl + og * 4 * D;
        float a0 = 0.f, a1 = 0.f, a2 = 0.f, a3 = 0.f;
#pragma unroll
        for (int k = 0; k < 64; k++) {
            float hk = hreg[k];
            a0 = fmaf(hk, w[k], a0);
            a1 = fmaf(hk, w[64 + k], a1);
            a2 = fmaf(hk, w[128 + k], a2);
            a3 = fmaf(hk, w[192 + k], a3);
        }
        yp[og] = make_float4(a0, a1, a2, a3);
    }
    for (int og = 0; og < 16; og++) {
        const float* w = Wr + og * 4 * D;
        float a0 = bl[og * 4], a1 = bl[og * 4 + 1];
        float a2 = bl[og * 4 + 2], a3 = bl[og * 4 + 3];
#pragma unroll
        for (int k = 0; k < 64; k++) {
            float hk = hreg[k];
            a0 = fmaf(hk, w[k], a0);
            a1 = fmaf(hk, w[64 + k], a1);
            a2 = fmaf(hk, w[128 + k], a2);
            a3 = fmaf(hk, w[192 + k], a3);
        }
        zp[og] = make_float4(a0, a1, a2, a3);
    }
}

// ---------------- SAGE gather: out = relu(mean_j Yl[j] + Zr[i]) ----------------
// 16 lanes per node (float4), 8-deep ILP.

__global__ __launch_bounds__(256) void sage_gather(const f4* __restrict__ Yl,
                                                   const f4* __restrict__ Zr,
                                                   const int* __restrict__ rowptr,
                                                   const int* __restrict__ col,
                                                   f4* __restrict__ out,
                                                   int relu_flag, int n) {
    int t = blockIdx.x * 256 + threadIdx.x;
    int l16 = t & 15;
    int gbase = (threadIdx.x & 63) & 48;
    int stride = (gridDim.x * 256) >> 4;
    for (int node = t >> 4; node < n; node += stride) {
        int start = rowptr[node], end = rowptr[node + 1];
        f4 a0 = {0, 0, 0, 0}, a1 = {0, 0, 0, 0}, a2 = {0, 0, 0, 0}, a3 = {0, 0, 0, 0};
        for (int base = start; base < end; base += 16) {
            int idx = base + l16;
            int s_l = (idx < end) ? col[idx] : 0;
            int cnt = min(16, end - base);
            int i = 0;
            for (; i + 7 < cnt; i += 8) {
                int s0 = __shfl(s_l, gbase + i);
                int s1 = __shfl(s_l, gbase + i + 1);
                int s2 = __shfl(s_l, gbase + i + 2);
                int s3 = __shfl(s_l, gbase + i + 3);
                int s4 = __shfl(s_l, gbase + i + 4);
                int s5 = __shfl(s_l, gbase + i + 5);
                int s6 = __shfl(s_l, gbase + i + 6);
                int s7 = __shfl(s_l, gbase + i + 7);
                f4 r0 = Yl[(size_t)s0 * D4 + l16];
                f4 r1 = Yl[(size_t)s1 * D4 + l16];
                f4 r2 = Yl[(size_t)s2 * D4 + l16];
                f4 r3 = Yl[(size_t)s3 * D4 + l16];
                f4 r4 = Yl[(size_t)s4 * D4 + l16];
                f4 r5 = Yl[(size_t)s5 * D4 + l16];
                f4 r6 = Yl[(size_t)s6 * D4 + l16];
                f4 r7 = Yl[(size_t)s7 * D4 + l16];
                a0 = f4add(a0, r0); a1 = f4add(a1, r1);
                a2 = f4add(a2, r2); a3 = f4add(a3, r3);
                a0 = f4add(a0, r4); a1 = f4add(a1, r5);
                a2 = f4add(a2, r6); a3 = f4add(a3, r7);
            }
            for (; i < cnt; i++) {
                int s = __shfl(s_l, gbase + i);
                a0 = f4add(a0, Yl[(size_t)s * D4 + l16]);
            }
        }
        f4 a = f4add(f4add(a0, a1), f4add(a2, a3));
        float invd = 1.f / fmaxf((float)(end - start), 1.f);
        f4 z = Zr[(size_t)node * D4 + l16];
        f4 o = make_float4(fmaf(a.x, invd, z.x), fmaf(a.y, invd, z.y),
                           fmaf(a.z, invd, z.z), fmaf(a.w, invd, z.w));
        if (relu_flag) {
            o.x = fmaxf(o.x, 0.f); o.y = fmaxf(o.y, 0.f);
            o.z = fmaxf(o.z, 0.f); o.w = fmaxf(o.w, 0.f);
        }
        out[(size_t)node * D4 + l16] = o;
    }
}

// ---------------- GAT dense: ht = h@W.T ; as = ht.a_src ; ad = ht.a_dst ----------------
// One thread per node; weights + attention vectors via scalar loads.

__global__ __launch_bounds__(256) void gat_transform(const float* __restrict__ h,
                                                     const float* __restrict__ W,
                                                     const float* __restrict__ a_src,
                                                     const float* __restrict__ a_dst,
                                                     float* __restrict__ ht,
                                                     float* __restrict__ as_,
                                                     float* __restrict__ ad_, int n) {
    int node = blockIdx.x * 256 + threadIdx.x;
    if (node >= n) return;
    float hreg[64];
    const f4* hp = (const f4*)(h + (size_t)node * D);
#pragma unroll
    for (int i = 0; i < 16; i++) {
        f4 r = hp[i];
        hreg[4 * i] = r.x; hreg[4 * i + 1] = r.y;
        hreg[4 * i + 2] = r.z; hreg[4 * i + 3] = r.w;
    }
    f4* hto = (f4*)(ht + (size_t)node * D);
    float s_acc = 0.f, d_acc = 0.f;
    for (int og = 0; og < 16; og++) {
        const float* w = W + og * 4 * D;
        float a0 = 0.f, a1 = 0.f, a2 = 0.f, a3 = 0.f;
#pragma unroll
        for (int k = 0; k < 64; k++) {
            float hk = hreg[k];
            a0 = fmaf(hk, w[k], a0);
            a1 = fmaf(hk, w[64 + k], a1);
            a2 = fmaf(hk, w[128 + k], a2);
            a3 = fmaf(hk, w[192 + k], a3);
        }
        hto[og] = make_float4(a0, a1, a2, a3);
        s_acc = fmaf(a0, a_src[og * 4], s_acc);
        s_acc = fmaf(a1, a_src[og * 4 + 1], s_acc);
        s_acc = fmaf(a2, a_src[og * 4 + 2], s_acc);
        s_acc = fmaf(a3, a_src[og * 4 + 3], s_acc);
        d_acc = fmaf(a0, a_dst[og * 4], d_acc);
        d_acc = fmaf(a1, a_dst[og * 4 + 1], d_acc);
        d_acc = fmaf(a2, a_dst[og * 4 + 2], d_acc);
        d_acc = fmaf(a3, a_dst[og * 4 + 3], d_acc);
    }
    as_[node] = s_acc;
    ad_[node] = d_acc;
}

// ---------------- GAT gather: single-pass online softmax + weighted agg ----------------

__global__ __launch_bounds__(256) void gat_gather(const int* __restrict__ rowptr,
                                                  const int* __restrict__ col,
                                                  const float* __restrict__ as_,
                                                  const float* __restrict__ ad_,
                                                  const f4* __restrict__ ht,
                                                  const float* __restrict__ b,
                                                  f4* __restrict__ out,
                                                  int relu_flag, int n) {
    int t = blockIdx.x * 256 + threadIdx.x;
    int l16 = t & 15;
    int gbase = (threadIdx.x & 63) & 48;
    int stride = (gridDim.x * 256) >> 4;
    const f4* b4 = (const f4*)b;
    for (int node = t >> 4; node < n; node += stride) {
        int start = rowptr[node], end = rowptr[node + 1];
        float ad_n = ad_[node];
        float e_self = leaky02(as_[node] + ad_n);
        float m = e_self;
        float z0 = 1.f, z1 = 0.f, z2 = 0.f, z3 = 0.f;
        f4 acc0 = ht[(size_t)node * D4 + l16];
        f4 acc1 = {0, 0, 0, 0}, acc2 = {0, 0, 0, 0}, acc3 = {0, 0, 0, 0};
        for (int base = start; base < end; base += 16) {
            int idx = base + l16;
            int cnt = min(16, end - base);
            int s_l = (idx < end) ? col[idx] : 0;
            float e_l = (idx < end) ? leaky02(as_[s_l] + ad_n) : -3.4e38f;
            float cm = e_l;
#pragma unroll
            for (int off = 8; off > 0; off >>= 1)
                cm = fmaxf(cm, __shfl_xor(cm, off));
            if (cm > m) {
                float sc = __expf(m - cm);
                z0 *= sc; z1 *= sc; z2 *= sc; z3 *= sc;
                acc0 = f4scale(acc0, sc); acc1 = f4scale(acc1, sc);
                acc2 = f4scale(acc2, sc); acc3 = f4scale(acc3, sc);
                m = cm;
            }
            float p_l = (idx < end) ? __expf(e_l - m) : 0.f;
            int i = 0;
            for (; i + 3 < cnt; i += 4) {
                int s0 = __shfl(s_l, gbase + i);
                int s1 = __shfl(s_l, gbase + i + 1);
                int s2 = __shfl(s_l, gbase + i + 2);
                int s3 = __shfl(s_l, gbase + i + 3);
                float p0 = __shfl(p_l, gbase + i);
                float p1 = __shfl(p_l, gbase + i + 1);
                float p2 = __shfl(p_l, gbase + i + 2);
                float p3 = __shfl(p_l, gbase + i + 3);
                f4 r0 = ht[(size_t)s0 * D4 + l16];
                f4 r1 = ht[(size_t)s1 * D4 + l16];
                f4 r2 = ht[(size_t)s2 * D4 + l16];
                f4 r3 = ht[(size_t)s3 * D4 + l16];
                z0 += p0; z1 += p1; z2 += p2; z3 += p3;
                acc0 = f4fma(p0, r0, acc0);
                acc1 = f4fma(p1, r1, acc1);
                acc2 = f4fma(p2, r2, acc2);
                acc3 = f4fma(p3, r3, acc3);
            }
            for (; i < cnt; i++) {
                int s0 = __shfl(s_l, gbase + i);
                float p0 = __shfl(p_l, gbase + i);
                z0 += p0;
                acc0 = f4fma(p0, ht[(size_t)s0 * D4 + l16], acc0);
            }
        }
        float rz = 1.f / ((z0 + z1) + (z2 + z3));
        f4 acc = f4add(f4add(acc0, acc1), f4add(acc2, acc3));
        f4 bb = b4[l16];
        f4 o = make_float4(fmaf(acc.x, rz, bb.x), fmaf(acc.y, rz, bb.y),
                           fmaf(acc.z, rz, bb.z), fmaf(acc.w, rz, bb.w));
        if (relu_flag) {
            o.x = fmaxf(o.x, 0.f); o.y = fmaxf(o.y, 0.f);
            o.z = fmaxf(o.z, 0.f); o.w = fmaxf(o.w, 0.f);
        }
        out[(size_t)node * D4 + l16] = o;
    }
}

// ---------------- MLP: one thread per node, scalar-loaded weights, fused layers ----------------

__global__ __launch_bounds__(256) void mlp_kernel(const float* __restrict__ h,
                                                  const float* __restrict__ W1,
                                                  const float* __restrict__ b1,
                                                  const float* __restrict__ W2,
                                                  const float* __restrict__ b2,
                                                  const float* __restrict__ W3,
                                                  const float* __restrict__ b3,
                                                  float* __restrict__ out, int n) {
    int node = blockIdx.x * 256 + threadIdx.x;
    if (node >= n) return;
    float hreg[64];
    const f4* hp = (const f4*)(h + (size_t)node * D);
#pragma unroll
    for (int i = 0; i < 16; i++) {
        f4 r = hp[i];
        hreg[4 * i] = r.x; hreg[4 * i + 1] = r.y;
        hreg[4 * i + 2] = r.z; hreg[4 * i + 3] = r.w;
    }
    // layer 1 (64->64, relu) fused with layer-2 accumulation (64->32)
    float v2[32];
#pragma unroll
    for (int o = 0; o < 32; o++) v2[o] = b2[o];
    for (int og = 0; og < 16; og++) {
        const float* w = W1 + og * 4 * 64;
        float a0 = b1[og * 4], a1 = b1[og * 4 + 1];
        float a2 = b1[og * 4 + 2], a3 = b1[og * 4 + 3];
#pragma unroll
        for (int k = 0; k < 64; k++) {
            float hk = hreg[k];
            a0 = fmaf(hk, w[k], a0);
            a1 = fmaf(hk, w[64 + k], a1);
            a2 = fmaf(hk, w[128 + k], a2);
            a3 = fmaf(hk, w[192 + k], a3);
        }
        a0 = fmaxf(a0, 0.f); a1 = fmaxf(a1, 0.f);
        a2 = fmaxf(a2, 0.f); a3 = fmaxf(a3, 0.f);
        const float* w2c = W2 + og * 4;   // column block og*4.. of W2[32][64]
#pragma unroll
        for (int o = 0; o < 32; o++) {
            v2[o] = fmaf(a0, w2c[o * 64], v2[o]);
            v2[o] = fmaf(a1, w2c[o * 64 + 1], v2[o]);
            v2[o] = fmaf(a2, w2c[o * 64 + 2], v2[o]);
            v2[o] = fmaf(a3, w2c[o * 64 + 3], v2[o]);
        }
    }
#pragma unroll
    for (int o = 0; o < 32; o++) v2[o] = fmaxf(v2[o], 0.f);
    // layer 3 (32->16)
    f4* op = (f4*)(out + (size_t)node * 16);
    for (int og = 0; og < 4; og++) {
        const float* w = W3 + og * 4 * 32;
        float a0 = b3[og * 4], a1 = b3[og * 4 + 1];
        float a2 = b3[og * 4 + 2], a3 = b3[og * 4 + 3];
#pragma unroll
        for (int k = 0; k < 32; k++) {
            float vk = v2[k];
            a0 = fmaf(vk, w[k], a0);
            a1 = fmaf(vk, w[32 + k], a1);
            a2 = fmaf(vk, w[64 + k], a2);
            a3 = fmaf(vk, w[96 + k], a3);
        }
        op[og] = make_float4(a0, a1, a2, a3);
    }
}

// ---------------- launch ----------------

extern "C" void kernel_launch(void* const* d_in, const int* in_sizes, int n_in,
                              void* d_out, int out_size, void* d_ws, size_t ws_size,
                              hipStream_t stream) {
    const int n  = in_sizes[0] / D;      // 100000
    const int ne = in_sizes[1] / 2;      // 1600000

    const float* x        = (const float*)d_in[0];
    const int*   ei       = (const int*)d_in[1];
    const int*   src      = ei;
    const int*   dst      = ei + ne;
    const float* sage_Wl  = (const float*)d_in[2];
    const float* sage_bl  = (const float*)d_in[3];
    const float* sage_Wr  = (const float*)d_in[4];
    const float* gat_W    = (const float*)d_in[5];
    const float* gat_asrc = (const float*)d_in[6];
    const float* gat_adst = (const float*)d_in[7];
    const float* gat_b    = (const float*)d_in[8];
    const float* W1 = (const float*)d_in[9];
    const float* b1 = (const float*)d_in[10];
    const float* W2 = (const float*)d_in[11];
    const float* b2 = (const float*)d_in[12];
    const float* W3 = (const float*)d_in[13];
    const float* b3 = (const float*)d_in[14];
    float* out = (float*)d_out;

    // workspace layout (4B units, all offsets 16B-aligned)
    int*   cnt      = (int*)d_ws;                    // n
    int*   incl     = cnt + n;                       // n
    int*   rowptr   = incl + n;                      // n+4
    int*   cursor   = rowptr + n + 4;                // n
    int*   partials = cursor + n;                    // 1024
    int*   col      = partials + 1024;               // ne
    float* as_      = (float*)(col + ne);            // n
    float* ad_      = as_ + n;                       // n
    float* Yl       = ad_ + n;                       // n*D (also GAT ht)
    float* Zr       = Yl + (size_t)n * D;            // n*D
    float* bufA     = Zr + (size_t)n * D;            // n*D
    float* bufB     = bufA + (size_t)n * D;          // n*D

    const int gridE  = (ne + 255) / 256;
    const int nb     = (n + SCAN_BS - 1) / SCAN_BS;
    const int gridG  = (n * 16 + 255) / 256;         // 16 lanes per node
    const int gridT  = (n + 255) / 256;              // 1 thread per node

    // ---- CSR build ----
    hipMemsetAsync(cnt, 0, (size_t)n * 4, stream);
    hist_kernel<<<gridE, 256, 0, stream>>>(dst, cnt, ne);
    scan1_kernel<<<nb, SCAN_BS, 0, stream>>>(cnt, incl, partials, n);
    scan2_kernel<<<1, 1024, 0, stream>>>(partials, nb);
    scan3_kernel<<<nb, SCAN_BS, 0, stream>>>(cnt, incl, partials, rowptr, cursor, n, ne);
    fill_kernel<<<gridE, 256, 0, stream>>>(src, dst, cursor, col, ne);

    // ---- 4 SAGE layers (x -> A -> B -> A -> B) ----
    const float* cur = x;
    float* nxt = bufA;
    for (int l = 0; l < 4; l++) {
        sage_dense<<<gridT, 256, 0, stream>>>(cur,
                                              sage_Wl + (size_t)l * D * D,
                                              sage_bl + (size_t)l * D,
                                              sage_Wr + (size_t)l * D * D,
                                              Yl, Zr, n);
        sage_gather<<<gridG, 256, 0, stream>>>((const f4*)Yl, (const f4*)Zr,
                                               rowptr, col, (f4*)nxt,
                                               (l < 3) ? 1 : 0, n);
        cur = nxt;
        nxt = (nxt == bufA) ? bufB : bufA;
    }
    // cur == bufB

    // ---- 4 GAT layers (in-place on bufB, ht reuses Yl) ----
    float* gin = bufB;
    for (int l = 0; l < 4; l++) {
        gat_transform<<<gridT, 256, 0, stream>>>(gin,
                                                 gat_W + (size_t)l * D * D,
                                                 gat_asrc + (size_t)l * D,
                                                 gat_adst + (size_t)l * D,
                                                 Yl, as_, ad_, n);
        gat_gather<<<gridG, 256, 0, stream>>>(rowptr, col, as_, ad_,
                                              (const f4*)Yl,
                                              gat_b + (size_t)l * D, (f4*)gin,
                                              (l < 3) ? 1 : 0, n);
    }

    // ---- projection MLP ----
    mlp_kernel<<<gridT, 256, 0, stream>>>(gin, W1, b1, W2, b2, W3, b3, out, n);
}